// Round 11
// baseline (217.816 us; speedup 1.0000x reference)
//
#include <hip/hip_runtime.h>
#include <hip/hip_bf16.h>
#include <math.h>

#define N_NODES 20000
#define N_EDGES 320000
#define IN_F 256
#define HID 64
#define HEADS 4
#define OUT_F 64
#define EDGE_F 16
#define NUM_CLASSES 10
#define NUM_GRAPHS 40
#define LRELU_ALPHA 0.2f

typedef short bf16x8 __attribute__((ext_vector_type(8)));
typedef unsigned short u16x8 __attribute__((ext_vector_type(8)));
typedef float f32x4 __attribute__((ext_vector_type(4)));

static __device__ __forceinline__ float bf2f(unsigned short u) {
    union { unsigned int i; float f; } v; v.i = ((unsigned int)u) << 16; return v.f;
}
static __device__ __forceinline__ unsigned short f2bf(float f) {
    union { float f; unsigned int i; } v; v.f = f;
    unsigned int r = v.i + 0x7FFF + ((v.i >> 16) & 1);
    return (unsigned short)(r >> 16);
}
static __device__ __forceinline__ float eluf(float a) {
    return a > 0.f ? a : __expf(a) - 1.0f;
}

// ---------------- prep: W0/W1 transpose->bf16 [n][k], W2 convert, zero cnt ----------------
__global__ void prep_kernel(const float* __restrict__ W0, const float* __restrict__ W1,
                            const float* __restrict__ W2, unsigned short* __restrict__ W0t,
                            unsigned short* __restrict__ W1t, unsigned short* __restrict__ W2b,
                            int* __restrict__ cnt) {
    int b = blockIdx.x, t = threadIdx.x;
    if (b < 32) {
        // transpose-convert one 64x64 tile of W0/W1 into [n][k] layout
        __shared__ unsigned short tl[64][65];
        const float* W = (b < 16) ? W0 : W1;
        unsigned short* Wt = (b < 16) ? W0t : W1t;
        int tile = b & 15;
        int tk = (tile >> 2) * 64, tn = (tile & 3) * 64;
        int kl = t >> 2, cg = (t & 3) * 16;
        const float* sp = W + (size_t)(tk + kl) * 256 + tn + cg;
#pragma unroll
        for (int q = 0; q < 4; ++q) {
            float4 v = ((const float4*)sp)[q];
            tl[kl][cg + q * 4 + 0] = f2bf(v.x);
            tl[kl][cg + q * 4 + 1] = f2bf(v.y);
            tl[kl][cg + q * 4 + 2] = f2bf(v.z);
            tl[kl][cg + q * 4 + 3] = f2bf(v.w);
        }
        __syncthreads();
        int nl = t >> 2, kg = (t & 3) * 16;
        u16x8 o0, o1;
#pragma unroll
        for (int q = 0; q < 8; ++q) { o0[q] = tl[kg + q][nl]; o1[q] = tl[kg + 8 + q][nl]; }
        unsigned short* dst = Wt + (size_t)(tn + nl) * 256 + tk + kg;
        *(u16x8*)dst = o0;
        *(u16x8*)(dst + 8) = o1;
    } else if (b < 48) {
        int i = (b - 32) * 256 + t;  // 4096 float4s of W2
        float4 v = ((const float4*)W2)[i];
        ushort4 o;
        o.x = f2bf(v.x); o.y = f2bf(v.y); o.z = f2bf(v.z); o.w = f2bf(v.w);
        ((ushort4*)W2b)[i] = o;
    } else {
        int j = (b - 48) * 256 + t;
        if (j < N_NODES / 4) ((int4*)cnt)[j] = make_int4(0, 0, 0, 0);
    }
}

// ---------------- CSR build ----------------
__global__ void count_kernel(const int4* __restrict__ src4, int* __restrict__ cnt) {
    int i = blockIdx.x * blockDim.x + threadIdx.x;
    if (i < N_EDGES / 4) {
        int4 s = src4[i];
        atomicAdd(&cnt[s.x], 1);
        atomicAdd(&cnt[s.y], 1);
        atomicAdd(&cnt[s.z], 1);
        atomicAdd(&cnt[s.w], 1);
    }
}

__global__ __launch_bounds__(1024) void scan_kernel(const int* __restrict__ cnt,
                                                    int* __restrict__ row_ptr,
                                                    int* __restrict__ cursor) {
    __shared__ int wsum[16];
    __shared__ int carry_s;
    int t = threadIdx.x;
    int lane = t & 63, wave = t >> 6;
    if (t == 0) { carry_s = 0; row_ptr[0] = 0; }
    __syncthreads();
    for (int base = 0; base < N_NODES; base += 1024) {
        int idx = base + t;
        int x0 = (idx < N_NODES) ? cnt[idx] : 0;
        int x = x0;
#pragma unroll
        for (int off = 1; off < 64; off <<= 1) {
            int y = __shfl_up(x, off, 64);
            if (lane >= off) x += y;
        }
        if (lane == 63) wsum[wave] = x;
        __syncthreads();
        if (wave == 0 && lane < 16) {
            int s = wsum[lane];
#pragma unroll
            for (int off = 1; off < 16; off <<= 1) {
                int y = __shfl_up(s, off, 64);
                if (lane >= off) s += y;
            }
            wsum[lane] = s;
        }
        __syncthreads();
        int waveoff = (wave > 0) ? wsum[wave - 1] : 0;
        int carry = carry_s;
        if (idx < N_NODES) {
            int incl = x + waveoff + carry;
            row_ptr[idx + 1] = incl;
            cursor[idx] = incl - x0;
        }
        __syncthreads();
        if (t == 0) carry_s = carry + wsum[15];
        __syncthreads();
    }
}

// scatter: two scattered 4B stores only (dstp + CSR->orig edge map)
__global__ void scatter_kernel(const int* __restrict__ src, const int* __restrict__ dst,
                               int* __restrict__ cursor, int* __restrict__ dstp,
                               int* __restrict__ perm) {
    int e = blockIdx.x * blockDim.x + threadIdx.x;
    if (e < N_EDGES) {
        int s = src[e];
        int pos = atomicAdd(&cursor[s], 1);
        dstp[pos] = dst[e];
        perm[pos] = e;
    }
}

// ---------------- gemm128: C[Mx256] = A[Mx256] * B, B pre-transposed [n][k] ----------------
// BM=BN=128, BK=32; 4 waves, each a 64x64 quadrant (16 MFMA : 8 ds_read_b128 per k-step).
// Register-pipelined staging; LDS-aliased two-half epilogue; fused per-row attention scores.
template <bool AF32, bool SCORES>
__global__ __launch_bounds__(256) void gemm128(const void* __restrict__ Aptr,
                                               const unsigned short* __restrict__ Bt,
                                               unsigned short* __restrict__ C,
                                               const float* __restrict__ avec,
                                               float* __restrict__ si, float* __restrict__ sj,
                                               int M) {
    __shared__ unsigned short smem[2 * 128 * 40];  // As | Bs ; aliased as Cs in epilogue
    __shared__ float sa[2][128];
    unsigned short (*As)[40] = (unsigned short(*)[40])smem;
    unsigned short (*Bs)[40] = (unsigned short(*)[40])(smem + 128 * 40);
    unsigned short (*Cs)[136] = (unsigned short(*)[136])smem;  // 64 x 136 <= 10240 shorts
    int tid = threadIdx.x;
    int bm = blockIdx.x * 128, bn = blockIdx.y * 128;
    if (SCORES) {
        int hh = tid >> 7, idx = tid & 127;
        sa[hh][idx] = avec[((bn >> 6) + hh) * 144 + idx];
    }
    int w = tid >> 6, l = tid & 63;
    int wr = (w >> 1) * 64, wc = (w & 1) * 64;
    int lr = l & 15, lk = (l >> 4) * 8;
    f32x4 acc[4][4] = {};
    int srow = tid >> 1, skc = (tid & 1) * 16;
    bool arow_ok = (bm + srow < M);
    const float* Af32 = (const float*)Aptr + (size_t)(bm + srow) * 256 + skc;
    const unsigned short* Ab16 = (const unsigned short*)Aptr + (size_t)(bm + srow) * 256 + skc;
    const unsigned short* Bb = Bt + (size_t)(bn + srow) * 256 + skc;

    bf16x8 av0 = {}, av1 = {}, bv0, bv1;
    // preload k0 = 0
    if (arow_ok) {
        if constexpr (AF32) {
            float4 f0 = ((const float4*)Af32)[0], f1 = ((const float4*)Af32)[1];
            float4 f2 = ((const float4*)Af32)[2], f3 = ((const float4*)Af32)[3];
            av0[0]=(short)f2bf(f0.x); av0[1]=(short)f2bf(f0.y); av0[2]=(short)f2bf(f0.z); av0[3]=(short)f2bf(f0.w);
            av0[4]=(short)f2bf(f1.x); av0[5]=(short)f2bf(f1.y); av0[6]=(short)f2bf(f1.z); av0[7]=(short)f2bf(f1.w);
            av1[0]=(short)f2bf(f2.x); av1[1]=(short)f2bf(f2.y); av1[2]=(short)f2bf(f2.z); av1[3]=(short)f2bf(f2.w);
            av1[4]=(short)f2bf(f3.x); av1[5]=(short)f2bf(f3.y); av1[6]=(short)f2bf(f3.z); av1[7]=(short)f2bf(f3.w);
        } else {
            av0 = *(const bf16x8*)(Ab16);
            av1 = *(const bf16x8*)(Ab16 + 8);
        }
    }
    bv0 = *(const bf16x8*)(Bb);
    bv1 = *(const bf16x8*)(Bb + 8);

    for (int k0 = 0; k0 < 256; k0 += 32) {
        *(bf16x8*)&As[srow][skc] = av0;
        *(bf16x8*)&As[srow][skc + 8] = av1;
        *(bf16x8*)&Bs[srow][skc] = bv0;
        *(bf16x8*)&Bs[srow][skc + 8] = bv1;
        if (k0 + 32 < 256) {
            // issue next k-step's loads; they complete under the MFMA block below
            if (arow_ok) {
                if constexpr (AF32) {
                    const float* p = Af32 + k0 + 32;
                    float4 f0 = ((const float4*)p)[0], f1 = ((const float4*)p)[1];
                    float4 f2 = ((const float4*)p)[2], f3 = ((const float4*)p)[3];
                    av0[0]=(short)f2bf(f0.x); av0[1]=(short)f2bf(f0.y); av0[2]=(short)f2bf(f0.z); av0[3]=(short)f2bf(f0.w);
                    av0[4]=(short)f2bf(f1.x); av0[5]=(short)f2bf(f1.y); av0[6]=(short)f2bf(f1.z); av0[7]=(short)f2bf(f1.w);
                    av1[0]=(short)f2bf(f2.x); av1[1]=(short)f2bf(f2.y); av1[2]=(short)f2bf(f2.z); av1[3]=(short)f2bf(f2.w);
                    av1[4]=(short)f2bf(f3.x); av1[5]=(short)f2bf(f3.y); av1[6]=(short)f2bf(f3.z); av1[7]=(short)f2bf(f3.w);
                } else {
                    av0 = *(const bf16x8*)(Ab16 + k0 + 32);
                    av1 = *(const bf16x8*)(Ab16 + k0 + 40);
                }
            }
            bv0 = *(const bf16x8*)(Bb + k0 + 32);
            bv1 = *(const bf16x8*)(Bb + k0 + 40);
        }
        __syncthreads();
        bf16x8 af[4], bfr[4];
#pragma unroll
        for (int i = 0; i < 4; ++i) af[i] = *(const bf16x8*)&As[wr + i * 16 + lr][lk];
#pragma unroll
        for (int j = 0; j < 4; ++j) bfr[j] = *(const bf16x8*)&Bs[wc + j * 16 + lr][lk];
#pragma unroll
        for (int i = 0; i < 4; ++i)
#pragma unroll
            for (int j = 0; j < 4; ++j)
                acc[i][j] = __builtin_amdgcn_mfma_f32_16x16x32_bf16(af[i], bfr[j], acc[i][j], 0, 0, 0);
        __syncthreads();
    }

    // epilogue in two 64-row halves over aliased Cs (D: col=lane&15, row=(lane>>4)*4+reg)
#pragma unroll
    for (int h = 0; h < 2; ++h) {
        if ((w >> 1) == h) {
#pragma unroll
            for (int i = 0; i < 4; ++i)
#pragma unroll
                for (int j = 0; j < 4; ++j)
#pragma unroll
                    for (int r = 0; r < 4; ++r)
                        Cs[i * 16 + (l >> 4) * 4 + r][wc + j * 16 + lr] = f2bf(acc[i][j][r]);
        }
        __syncthreads();
        int row = tid >> 2;
        int grow = bm + h * 64 + row;
        if (grow < M) {
            int c0 = (tid & 3) * 8;
#pragma unroll
            for (int q = 0; q < 4; ++q) {
                bf16x8 o = *(const bf16x8*)&Cs[row][c0 + q * 32];
                *(bf16x8*)(C + (size_t)grow * 256 + bn + c0 + q * 32) = o;
            }
        }
        if (SCORES) {
            int q = tid & 3, hl = q >> 1, sel = q & 1;
            float s = 0.f;
#pragma unroll
            for (int c = 0; c < 64; ++c)
                s += bf2f(Cs[row][hl * 64 + c]) * sa[hl][sel * 64 + c];
            if (grow < M) {
                int head = (bn >> 6) + hl;
                if (sel == 0) si[(size_t)grow * 4 + head] = s;
                else          sj[(size_t)grow * 4 + head] = s;
            }
        }
        __syncthreads();
    }
}

// ---------------- old gemm (layer 2 only: N=64, B in [k][n], no scores) ----------------
__global__ __launch_bounds__(256) void gemm64(const unsigned short* __restrict__ Aptr,
                                              const unsigned short* __restrict__ B,
                                              unsigned short* __restrict__ C,
                                              int M, int N, int K) {
    __shared__ unsigned short As[128][40];
    __shared__ unsigned short Bs[64][40];
    __shared__ unsigned short Cs[128][72];
    int tid = threadIdx.x;
    int bm = blockIdx.x * 128, bn = 0;
    int w = tid >> 6, l = tid & 63;
    int wr = w * 32;
    int lr = l & 15, lk = (l >> 4) * 8;
    f32x4 acc[2][4] = {};
    int ar = tid >> 1, akc = (tid & 1) * 16;
    int bk = tid >> 3, bn8 = tid & 7, bnc = bn8 * 8;

    for (int k0 = 0; k0 < K; k0 += 32) {
        bf16x8 av0 = {}, av1 = {};
        if (bm + ar < M) {
            const unsigned short* Ab = Aptr + (size_t)(bm + ar) * K + k0 + akc;
            av0 = *(const bf16x8*)Ab;
            av1 = *(const bf16x8*)(Ab + 8);
        }
        *(bf16x8*)&As[ar][akc] = av0;
        *(bf16x8*)&As[ar][akc + 8] = av1;
        bf16x8 bv = *(const bf16x8*)(B + (size_t)(k0 + bk) * N + bn + bnc);
#pragma unroll
        for (int j = 0; j < 8; ++j) {
            int jj = (j + bn8) & 7;
            Bs[bnc + jj][bk] = (unsigned short)bv[jj];
        }
        __syncthreads();
        bf16x8 a0 = *(const bf16x8*)&As[wr + lr][lk];
        bf16x8 a1 = *(const bf16x8*)&As[wr + 16 + lr][lk];
        bf16x8 b0 = *(const bf16x8*)&Bs[lr][lk];
        bf16x8 b1 = *(const bf16x8*)&Bs[16 + lr][lk];
        bf16x8 b2 = *(const bf16x8*)&Bs[32 + lr][lk];
        bf16x8 b3 = *(const bf16x8*)&Bs[48 + lr][lk];
        acc[0][0] = __builtin_amdgcn_mfma_f32_16x16x32_bf16(a0, b0, acc[0][0], 0, 0, 0);
        acc[0][1] = __builtin_amdgcn_mfma_f32_16x16x32_bf16(a0, b1, acc[0][1], 0, 0, 0);
        acc[0][2] = __builtin_amdgcn_mfma_f32_16x16x32_bf16(a0, b2, acc[0][2], 0, 0, 0);
        acc[0][3] = __builtin_amdgcn_mfma_f32_16x16x32_bf16(a0, b3, acc[0][3], 0, 0, 0);
        acc[1][0] = __builtin_amdgcn_mfma_f32_16x16x32_bf16(a1, b0, acc[1][0], 0, 0, 0);
        acc[1][1] = __builtin_amdgcn_mfma_f32_16x16x32_bf16(a1, b1, acc[1][1], 0, 0, 0);
        acc[1][2] = __builtin_amdgcn_mfma_f32_16x16x32_bf16(a1, b2, acc[1][2], 0, 0, 0);
        acc[1][3] = __builtin_amdgcn_mfma_f32_16x16x32_bf16(a1, b3, acc[1][3], 0, 0, 0);
        __syncthreads();
    }
#pragma unroll
    for (int i = 0; i < 2; ++i)
#pragma unroll
        for (int j = 0; j < 4; ++j)
#pragma unroll
            for (int r = 0; r < 4; ++r)
                Cs[wr + i * 16 + (l >> 4) * 4 + r][j * 16 + (l & 15)] = f2bf(acc[i][j][r]);
    __syncthreads();
    int row = tid >> 3, cc = (tid & 7) * 8;
#pragma unroll
    for (int p = 0; p < 4; ++p, row += 32) {
        if (bm + row < M) {
            bf16x8 o = *(const bf16x8*)&Cs[row][cc];
            *(bf16x8*)(C + (size_t)(bm + row) * N + cc) = o;
        }
    }
}

// ---------------- per-edge attention (original edge order, all coalesced) ----------------
__global__ void att_kernel(const int* __restrict__ src, const int* __restrict__ dst,
                           const float* __restrict__ ea, const float* __restrict__ avec,
                           const float* __restrict__ si, const float* __restrict__ sj,
                           float4* __restrict__ attp) {
    __shared__ float ae[4][16];
    int tid = threadIdx.x;
    if (tid < 64) ae[tid >> 4][tid & 15] = avec[(tid >> 4) * 144 + 128 + (tid & 15)];
    __syncthreads();
    int e = blockIdx.x * blockDim.x + tid;
    if (e >= N_EDGES) return;
    int s = src[e], u = dst[e];
    float4 siv = ((const float4*)si)[s];
    float4 sjv = ((const float4*)sj)[u];
    float x[16];
#pragma unroll
    for (int k = 0; k < 16; k += 4) {
        float4 v = *(const float4*)(ea + (size_t)e * 16 + k);
        x[k] = v.x; x[k + 1] = v.y; x[k + 2] = v.z; x[k + 3] = v.w;
    }
    float se0 = 0.f, se1 = 0.f, se2 = 0.f, se3 = 0.f;
#pragma unroll
    for (int k = 0; k < 16; ++k) {
        se0 += x[k] * ae[0][k];
        se1 += x[k] * ae[1][k];
        se2 += x[k] * ae[2][k];
        se3 += x[k] * ae[3][k];
    }
    float t0 = siv.x + sjv.x + se0;
    float t1 = siv.y + sjv.y + se1;
    float t2 = siv.z + sjv.z + se2;
    float t3 = siv.w + sjv.w + se3;
    t0 = t0 > 0.f ? t0 : LRELU_ALPHA * t0;
    t1 = t1 > 0.f ? t1 : LRELU_ALPHA * t1;
    t2 = t2 > 0.f ? t2 : LRELU_ALPHA * t2;
    t3 = t3 > 0.f ? t3 : LRELU_ALPHA * t3;
    float m = fmaxf(fmaxf(t0, t1), fmaxf(t2, t3));
    float p0 = __expf(t0 - m), p1 = __expf(t1 - m), p2 = __expf(t2 - m), p3 = __expf(t3 - m);
    float inv = 1.0f / (p0 + p1 + p2 + p3);
    attp[e] = make_float4(p0 * inv, p1 * inv, p2 * inv, p3 * inv);  // coalesced
}

// ---------------- edge aggregation, 4 heads, concat + ELU ----------------
// 4 edge-slots x 16 lanes; attp read via perm (broadcast 16B, prefetched under row gather)
__global__ __launch_bounds__(256) void edge_agg_concat(
    const unsigned short* __restrict__ Whb, const float4* __restrict__ attp,
    const int* __restrict__ row_ptr, const int* __restrict__ dstp,
    const int* __restrict__ perm, unsigned short* __restrict__ out) {
    int v = blockIdx.x * 4 + (threadIdx.x >> 6);
    if (v >= N_NODES) return;
    int l = threadIdx.x & 63;
    int slot = l >> 4, p = l & 15;
    int beg = row_ptr[v], end = row_ptr[v + 1];
    float acc0[8] = {}, acc1[8] = {};
    int i = beg + slot;
    int u_n = 0;
    float4 at_n = make_float4(0.f, 0.f, 0.f, 0.f);
    if (i < end) { u_n = dstp[i]; at_n = attp[perm[i]]; }
    for (; i < end; i += 4) {
        int u = u_n;
        float4 at4 = at_n;
        if (i + 4 < end) { u_n = dstp[i + 4]; at_n = attp[perm[i + 4]]; }
        const unsigned short* row = Whb + (size_t)u * 256;
        u16x8 w0 = *(const u16x8*)(row + p * 8);         // heads 0/1
        u16x8 w1 = *(const u16x8*)(row + 128 + p * 8);   // heads 2/3
        float atA = (p & 8) ? at4.y : at4.x;
        float atB = (p & 8) ? at4.w : at4.z;
#pragma unroll
        for (int j = 0; j < 8; ++j) acc0[j] += atA * bf2f(w0[j]);
#pragma unroll
        for (int j = 0; j < 8; ++j) acc1[j] += atB * bf2f(w1[j]);
    }
#pragma unroll
    for (int j = 0; j < 8; ++j) {
        acc0[j] += __shfl_xor(acc0[j], 16, 64);
        acc0[j] += __shfl_xor(acc0[j], 32, 64);
        acc1[j] += __shfl_xor(acc1[j], 16, 64);
        acc1[j] += __shfl_xor(acc1[j], 32, 64);
    }
    if (slot == 0) {
        u16x8 o0, o1;
#pragma unroll
        for (int j = 0; j < 8; ++j) {
            o0[j] = f2bf(eluf(acc0[j]));
            o1[j] = f2bf(eluf(acc1[j]));
        }
        *(u16x8*)(out + (size_t)v * 256 + p * 8) = o0;
        *(u16x8*)(out + (size_t)v * 256 + 128 + p * 8) = o1;
    }
}

// ---------------- edge aggregation, single head: 8 slots x 8 lanes ----------------
__global__ __launch_bounds__(256) void edge_agg_single(
    const unsigned short* __restrict__ Whb, const int* __restrict__ row_ptr,
    const int* __restrict__ dstp, float* __restrict__ out) {
    int v = blockIdx.x * 4 + (threadIdx.x >> 6);
    if (v >= N_NODES) return;
    int l = threadIdx.x & 63;
    int slot = l >> 3, p = l & 7;
    int beg = row_ptr[v], end = row_ptr[v + 1];
    float acc[8] = {};
    int i = beg + slot;
    int u_n = 0;
    if (i < end) u_n = dstp[i];
    for (; i < end; i += 8) {
        int u = u_n;
        if (i + 8 < end) u_n = dstp[i + 8];
        u16x8 w = *(const u16x8*)(Whb + (size_t)u * 64 + p * 8);
#pragma unroll
        for (int j = 0; j < 8; ++j) acc[j] += bf2f(w[j]);
    }
#pragma unroll
    for (int j = 0; j < 8; ++j) {
        acc[j] += __shfl_xor(acc[j], 8, 64);
        acc[j] += __shfl_xor(acc[j], 16, 64);
        acc[j] += __shfl_xor(acc[j], 32, 64);
    }
    if (l < 8) {
        float4 o0 = make_float4(acc[0], acc[1], acc[2], acc[3]);
        float4 o1 = make_float4(acc[4], acc[5], acc[6], acc[7]);
        *(float4*)(out + (size_t)v * 64 + p * 8) = o0;
        *(float4*)(out + (size_t)v * 64 + p * 8 + 4) = o1;
    }
}

// ---------------- mean pool per graph (batch sorted), 16 waves per graph ----------------
__global__ __launch_bounds__(1024) void pool_kernel(const float* __restrict__ h3,
                                                    const int* __restrict__ batch,
                                                    float* __restrict__ pooled) {
    int g = blockIdx.x;
    int lane = threadIdx.x & 63;
    int wave = threadIdx.x >> 6;
    int lo = 0, hi = N_NODES;
    while (lo < hi) { int mid = (lo + hi) >> 1; if (batch[mid] < g) lo = mid + 1; else hi = mid; }
    int start = lo;
    lo = start; hi = N_NODES;
    while (lo < hi) { int mid = (lo + hi) >> 1; if (batch[mid] < g + 1) lo = mid + 1; else hi = mid; }
    int endi = lo;
    float s = 0.f;
    for (int v = start + wave; v < endi; v += 16) s += h3[(size_t)v * 64 + lane];
    __shared__ float red[16][64];
    red[wave][lane] = s;
    __syncthreads();
    if (wave == 0) {
        float t = red[0][lane];
#pragma unroll
        for (int w = 1; w < 16; ++w) t += red[w][lane];
        float c = (float)((endi - start) > 1 ? (endi - start) : 1);
        pooled[g * 64 + lane] = t / c;
    }
}

// ---------------- classifier + log_softmax ----------------
__global__ void classify_kernel(const float* __restrict__ pooled, const float* __restrict__ cw,
                                const float* __restrict__ cb, float* __restrict__ out) {
    int g = threadIdx.x;
    if (g >= NUM_GRAPHS) return;
    float lg[NUM_CLASSES];
#pragma unroll
    for (int c = 0; c < NUM_CLASSES; ++c) lg[c] = cb[c];
    for (int d = 0; d < OUT_F; ++d) {
        float p = pooled[g * 64 + d];
#pragma unroll
        for (int c = 0; c < NUM_CLASSES; ++c) lg[c] += p * cw[d * NUM_CLASSES + c];
    }
    float m = lg[0];
#pragma unroll
    for (int c = 1; c < NUM_CLASSES; ++c) m = fmaxf(m, lg[c]);
    float s = 0.f;
#pragma unroll
    for (int c = 0; c < NUM_CLASSES; ++c) s += expf(lg[c] - m);
    float lse = m + logf(s);
#pragma unroll
    for (int c = 0; c < NUM_CLASSES; ++c) out[g * NUM_CLASSES + c] = lg[c] - lse;
}

extern "C" void kernel_launch(void* const* d_in, const int* in_sizes, int n_in,
                              void* d_out, int out_size, void* d_ws, size_t ws_size,
                              hipStream_t stream) {
    const float* x   = (const float*)d_in[0];
    const int*   ei  = (const int*)d_in[1];
    const float* ea  = (const float*)d_in[2];
    const int* batch = (const int*)d_in[3];
    const float* W0  = (const float*)d_in[4];
    const float* a0  = (const float*)d_in[5];
    const float* W1  = (const float*)d_in[6];
    const float* a1  = (const float*)d_in[7];
    const float* W2  = (const float*)d_in[8];
    const float* cw  = (const float*)d_in[10];
    const float* cb  = (const float*)d_in[11];
    float* out = (float*)d_out;

    const int* srcg = ei;
    const int* dstg = ei + N_EDGES;

    char* ws = (char*)d_ws;
    size_t off = 0;
    auto alloc = [&](size_t bytes) -> char* {
        char* p = ws + off;
        off += (bytes + 255) & ~(size_t)255;
        return p;
    };
    unsigned short* W0t  = (unsigned short*)alloc(256 * 256 * 2);   // [n][k]
    unsigned short* W1t  = (unsigned short*)alloc(256 * 256 * 2);   // [n][k]
    unsigned short* W2b  = (unsigned short*)alloc(256 * 64 * 2);    // [k][n]
    unsigned short* Whb  = (unsigned short*)alloc((size_t)N_NODES * 256 * 2);
    unsigned short* hAb  = (unsigned short*)alloc((size_t)N_NODES * 256 * 2);
    unsigned short* hBb  = (unsigned short*)alloc((size_t)N_NODES * 256 * 2);
    unsigned short* Wh2b = (unsigned short*)alloc((size_t)N_NODES * 64 * 2);
    float* si   = (float*)alloc((size_t)N_NODES * HEADS * 4);
    float* sj   = (float*)alloc((size_t)N_NODES * HEADS * 4);
    float* attp = (float*)alloc((size_t)N_EDGES * HEADS * 4);
    int* row_ptr = (int*)alloc((N_NODES + 1) * 4);
    int* cursor  = (int*)alloc(N_NODES * 4);
    int* cnt  = (int*)alloc(N_NODES * 4);
    int* dstp = (int*)alloc(N_EDGES * 4);
    int* perm = (int*)alloc(N_EDGES * 4);
    float* h3 = (float*)alloc((size_t)N_NODES * 64 * 4);
    float* pooled = (float*)alloc(NUM_GRAPHS * 64 * 4);

    // prep: W0/W1 transpose-convert, W2 convert, zero cnt
    prep_kernel<<<48 + (N_NODES / 4 + 255) / 256, 256, 0, stream>>>(W0, W1, W2, W0t, W1t, W2b, cnt);

    // CSR build (payload-free permutation)
    count_kernel<<<(N_EDGES / 4 + 255) / 256, 256, 0, stream>>>((const int4*)srcg, cnt);
    scan_kernel<<<1, 1024, 0, stream>>>(cnt, row_ptr, cursor);
    scatter_kernel<<<(N_EDGES + 255) / 256, 256, 0, stream>>>(srcg, dstg, cursor, dstp, perm);

    dim3 g128((N_NODES + 127) / 128, 2);
    int g64 = (N_NODES + 127) / 128;
    int atb = (N_EDGES + 255) / 256;
    int agb = (N_NODES + 3) / 4;

    // layer 0 (A = x fp32, scores fused)
    gemm128<true, true><<<g128, 256, 0, stream>>>(x, W0t, Whb, a0, si, sj, N_NODES);
    att_kernel<<<atb, 256, 0, stream>>>(srcg, dstg, ea, a0, si, sj, (float4*)attp);
    edge_agg_concat<<<agb, 256, 0, stream>>>(Whb, (const float4*)attp, row_ptr, dstp, perm, hAb);

    // layer 1
    gemm128<false, true><<<g128, 256, 0, stream>>>(hAb, W1t, Whb, a1, si, sj, N_NODES);
    att_kernel<<<atb, 256, 0, stream>>>(srcg, dstg, ea, a1, si, sj, (float4*)attp);
    edge_agg_concat<<<agb, 256, 0, stream>>>(Whb, (const float4*)attp, row_ptr, dstp, perm, hBb);

    // layer 2 (single head, att == 1, mean over 1 head = identity)
    gemm64<<<g64, 256, 0, stream>>>(hBb, W2b, Wh2b, N_NODES, 64, 256);
    edge_agg_single<<<agb, 256, 0, stream>>>(Wh2b, row_ptr, dstp, h3);

    // pooling + classifier
    pool_kernel<<<NUM_GRAPHS, 1024, 0, stream>>>(h3, batch, pooled);
    classify_kernel<<<1, 64, 0, stream>>>(pooled, cw, cb, out);
}

// Round 12
// 210.979 us; speedup vs baseline: 1.0324x; 1.0324x over previous
//
#include <hip/hip_runtime.h>
#include <hip/hip_bf16.h>
#include <math.h>

#define N_NODES 20000
#define N_EDGES 320000
#define IN_F 256
#define HID 64
#define HEADS 4
#define OUT_F 64
#define EDGE_F 16
#define NUM_CLASSES 10
#define NUM_GRAPHS 40
#define LRELU_ALPHA 0.2f

typedef short bf16x8 __attribute__((ext_vector_type(8)));
typedef unsigned short u16x8 __attribute__((ext_vector_type(8)));
typedef float f32x4 __attribute__((ext_vector_type(4)));

static __device__ __forceinline__ float bf2f(unsigned short u) {
    union { unsigned int i; float f; } v; v.i = ((unsigned int)u) << 16; return v.f;
}
static __device__ __forceinline__ unsigned short f2bf(float f) {
    union { float f; unsigned int i; } v; v.f = f;
    unsigned int r = v.i + 0x7FFF + ((v.i >> 16) & 1);
    return (unsigned short)(r >> 16);
}
static __device__ __forceinline__ float eluf(float a) {
    return a > 0.f ? a : __expf(a) - 1.0f;
}

// ---------------- prep: weight converts (bf16) + zero cnt, one dispatch ----------------
__global__ void prep_kernel(const float* __restrict__ W0, const float* __restrict__ W1,
                            const float* __restrict__ W2, unsigned short* __restrict__ W0b,
                            unsigned short* __restrict__ W1b, unsigned short* __restrict__ W2b,
                            int* __restrict__ cnt) {
    int b = blockIdx.x;
    if (b < 144) {
        int i = b * 256 + threadIdx.x;  // float4 units
        const float* src; unsigned short* dst; int off;
        if (i < 16384)      { src = W0; dst = W0b; off = i; }
        else if (i < 32768) { src = W1; dst = W1b; off = i - 16384; }
        else                { src = W2; dst = W2b; off = i - 32768; }
        float4 v = ((const float4*)src)[off];
        ushort4 o;
        o.x = f2bf(v.x); o.y = f2bf(v.y); o.z = f2bf(v.z); o.w = f2bf(v.w);
        ((ushort4*)dst)[off] = o;
    } else {
        int j = (b - 144) * 256 + threadIdx.x;  // int4 units
        if (j < N_NODES / 4) ((int4*)cnt)[j] = make_int4(0, 0, 0, 0);
    }
}

// ---------------- CSR build ----------------
__global__ void count_kernel(const int4* __restrict__ src4, int* __restrict__ cnt) {
    int i = blockIdx.x * blockDim.x + threadIdx.x;
    if (i < N_EDGES / 4) {
        int4 s = src4[i];
        atomicAdd(&cnt[s.x], 1);
        atomicAdd(&cnt[s.y], 1);
        atomicAdd(&cnt[s.z], 1);
        atomicAdd(&cnt[s.w], 1);
    }
}

// scan: row_ptr (inclusive shifted) + cursor = exclusive prefix (row start offsets)
__global__ __launch_bounds__(1024) void scan_kernel(const int* __restrict__ cnt,
                                                    int* __restrict__ row_ptr,
                                                    int* __restrict__ cursor) {
    __shared__ int wsum[16];
    __shared__ int carry_s;
    int t = threadIdx.x;
    int lane = t & 63, wave = t >> 6;
    if (t == 0) { carry_s = 0; row_ptr[0] = 0; }
    __syncthreads();
    for (int base = 0; base < N_NODES; base += 1024) {
        int idx = base + t;
        int x0 = (idx < N_NODES) ? cnt[idx] : 0;
        int x = x0;
#pragma unroll
        for (int off = 1; off < 64; off <<= 1) {
            int y = __shfl_up(x, off, 64);
            if (lane >= off) x += y;
        }
        if (lane == 63) wsum[wave] = x;
        __syncthreads();
        if (wave == 0 && lane < 16) {
            int s = wsum[lane];
#pragma unroll
            for (int off = 1; off < 16; off <<= 1) {
                int y = __shfl_up(s, off, 64);
                if (lane >= off) s += y;
            }
            wsum[lane] = s;
        }
        __syncthreads();
        int waveoff = (wave > 0) ? wsum[wave - 1] : 0;
        int carry = carry_s;
        if (idx < N_NODES) {
            int incl = x + waveoff + carry;
            row_ptr[idx + 1] = incl;
            cursor[idx] = incl - x0;   // row start
        }
        __syncthreads();
        if (t == 0) carry_s = carry + wsum[15];
        __syncthreads();
    }
}

// scatter: CSR-ordered src/dst + per-edge edge-feature scores (both layers) as bf16x8
// (one 16B scattered store instead of two float4 stores -> halves dirtied write lines)
__global__ void scatter_kernel(const int* __restrict__ src, const int* __restrict__ dst,
                               const float* __restrict__ ea, const float* __restrict__ a0,
                               const float* __restrict__ a1, int* __restrict__ cursor,
                               int* __restrict__ srcp, int* __restrict__ dstp,
                               unsigned short* __restrict__ se01b) {
    __shared__ float ae[2][4][16];
    int tid = threadIdx.x;
    if (tid < 64) ae[0][tid >> 4][tid & 15] = a0[(tid >> 4) * 144 + 128 + (tid & 15)];
    else if (tid < 128) { int t = tid - 64; ae[1][t >> 4][t & 15] = a1[(t >> 4) * 144 + 128 + (t & 15)]; }
    __syncthreads();
    int e = blockIdx.x * blockDim.x + tid;
    if (e >= N_EDGES) return;
    int s = src[e];
    int pos = atomicAdd(&cursor[s], 1);
    srcp[pos] = s;
    dstp[pos] = dst[e];
    float x[16];
#pragma unroll
    for (int k = 0; k < 16; k += 4) {
        float4 v = *(const float4*)(ea + (size_t)e * 16 + k);
        x[k] = v.x; x[k + 1] = v.y; x[k + 2] = v.z; x[k + 3] = v.w;
    }
    float o[8] = {};
#pragma unroll
    for (int k = 0; k < 16; ++k) {
        o[0] += x[k] * ae[0][0][k]; o[1] += x[k] * ae[0][1][k];
        o[2] += x[k] * ae[0][2][k]; o[3] += x[k] * ae[0][3][k];
        o[4] += x[k] * ae[1][0][k]; o[5] += x[k] * ae[1][1][k];
        o[6] += x[k] * ae[1][2][k]; o[7] += x[k] * ae[1][3][k];
    }
    u16x8 ob;
#pragma unroll
    for (int q = 0; q < 8; ++q) ob[q] = f2bf(o[q]);
    *(u16x8*)(se01b + (size_t)pos * 8) = ob;
}

// ---------------- bf16 MFMA GEMM (BM=128,BN=64,BK=32) + fused attention scores ----------------
template <bool AF32, bool SCORES>
__global__ __launch_bounds__(256) void gemm_bf16(const void* __restrict__ Aptr,
                                                 const unsigned short* __restrict__ B,
                                                 unsigned short* __restrict__ C,
                                                 const float* __restrict__ avec,
                                                 float* __restrict__ si, float* __restrict__ sj,
                                                 int M, int N, int K) {
    __shared__ unsigned short As[128][40];
    __shared__ unsigned short Bs[64][40];   // [n][k] (transposed)
    __shared__ unsigned short Cs[128][72];
    __shared__ float sa[128];
    int tid = threadIdx.x;
    if (SCORES && tid < 128) sa[tid] = avec[blockIdx.y * 144 + tid];
    int bm = blockIdx.x * 128, bn = blockIdx.y * 64;
    int w = tid >> 6, l = tid & 63;
    int wr = w * 32;
    int lr = l & 15, lk = (l >> 4) * 8;
    f32x4 acc[2][4] = {};
    int ar = tid >> 1, akc = (tid & 1) * 16;
    int bk = tid >> 3, bn8 = tid & 7, bnc = bn8 * 8;

    for (int k0 = 0; k0 < K; k0 += 32) {
        bf16x8 av0 = {}, av1 = {};
        if (bm + ar < M) {
            if constexpr (AF32) {
                const float* Af = (const float*)Aptr + (size_t)(bm + ar) * K + k0 + akc;
                float4 f0 = ((const float4*)Af)[0];
                float4 f1 = ((const float4*)Af)[1];
                float4 f2 = ((const float4*)Af)[2];
                float4 f3 = ((const float4*)Af)[3];
                av0[0] = (short)f2bf(f0.x); av0[1] = (short)f2bf(f0.y);
                av0[2] = (short)f2bf(f0.z); av0[3] = (short)f2bf(f0.w);
                av0[4] = (short)f2bf(f1.x); av0[5] = (short)f2bf(f1.y);
                av0[6] = (short)f2bf(f1.z); av0[7] = (short)f2bf(f1.w);
                av1[0] = (short)f2bf(f2.x); av1[1] = (short)f2bf(f2.y);
                av1[2] = (short)f2bf(f2.z); av1[3] = (short)f2bf(f2.w);
                av1[4] = (short)f2bf(f3.x); av1[5] = (short)f2bf(f3.y);
                av1[6] = (short)f2bf(f3.z); av1[7] = (short)f2bf(f3.w);
            } else {
                const unsigned short* Ab = (const unsigned short*)Aptr + (size_t)(bm + ar) * K + k0 + akc;
                av0 = *(const bf16x8*)Ab;
                av1 = *(const bf16x8*)(Ab + 8);
            }
        }
        *(bf16x8*)&As[ar][akc] = av0;
        *(bf16x8*)&As[ar][akc + 8] = av1;
        bf16x8 bv = *(const bf16x8*)(B + (size_t)(k0 + bk) * N + bn + bnc);
#pragma unroll
        for (int j = 0; j < 8; ++j) {
            int jj = (j + bn8) & 7;  // rotate write order to spread banks
            Bs[bnc + jj][bk] = (unsigned short)bv[jj];
        }
        __syncthreads();
        bf16x8 a0 = *(const bf16x8*)&As[wr + lr][lk];
        bf16x8 a1 = *(const bf16x8*)&As[wr + 16 + lr][lk];
        bf16x8 b0 = *(const bf16x8*)&Bs[lr][lk];
        bf16x8 b1 = *(const bf16x8*)&Bs[16 + lr][lk];
        bf16x8 b2 = *(const bf16x8*)&Bs[32 + lr][lk];
        bf16x8 b3 = *(const bf16x8*)&Bs[48 + lr][lk];
        acc[0][0] = __builtin_amdgcn_mfma_f32_16x16x32_bf16(a0, b0, acc[0][0], 0, 0, 0);
        acc[0][1] = __builtin_amdgcn_mfma_f32_16x16x32_bf16(a0, b1, acc[0][1], 0, 0, 0);
        acc[0][2] = __builtin_amdgcn_mfma_f32_16x16x32_bf16(a0, b2, acc[0][2], 0, 0, 0);
        acc[0][3] = __builtin_amdgcn_mfma_f32_16x16x32_bf16(a0, b3, acc[0][3], 0, 0, 0);
        acc[1][0] = __builtin_amdgcn_mfma_f32_16x16x32_bf16(a1, b0, acc[1][0], 0, 0, 0);
        acc[1][1] = __builtin_amdgcn_mfma_f32_16x16x32_bf16(a1, b1, acc[1][1], 0, 0, 0);
        acc[1][2] = __builtin_amdgcn_mfma_f32_16x16x32_bf16(a1, b2, acc[1][2], 0, 0, 0);
        acc[1][3] = __builtin_amdgcn_mfma_f32_16x16x32_bf16(a1, b3, acc[1][3], 0, 0, 0);
        __syncthreads();
    }
    // D layout: col = lane&15, row = (lane>>4)*4 + reg
#pragma unroll
    for (int i = 0; i < 2; ++i)
#pragma unroll
        for (int j = 0; j < 4; ++j)
#pragma unroll
            for (int r = 0; r < 4; ++r)
                Cs[wr + i * 16 + (l >> 4) * 4 + r][j * 16 + (l & 15)] = f2bf(acc[i][j][r]);
    __syncthreads();
    {
        int row = tid >> 3, cc = (tid & 7) * 8;
#pragma unroll
        for (int p = 0; p < 4; ++p, row += 32) {
            if (bm + row < M) {
                bf16x8 o = *(const bf16x8*)&Cs[row][cc];
                *(bf16x8*)(C + (size_t)(bm + row) * N + bn + cc) = o;
            }
        }
    }
    if (SCORES) {
        int r = tid >> 1, half = tid & 1;
        float s0 = 0.f, s1 = 0.f;
#pragma unroll
        for (int k = 0; k < 32; ++k) {
            float f = bf2f(Cs[r][half * 32 + k]);
            s0 += f * sa[half * 32 + k];
            s1 += f * sa[64 + half * 32 + k];
        }
        s0 += __shfl_xor(s0, 1, 64);
        s1 += __shfl_xor(s1, 1, 64);
        if (half == 0 && bm + r < M) {
            si[(size_t)(bm + r) * 4 + blockIdx.y] = s0;
            sj[(size_t)(bm + r) * 4 + blockIdx.y] = s1;
        }
    }
}

// ---------------- per-edge attention (CSR order, coalesced; bf16 se01) ----------------
__global__ void att_kernel(const int* __restrict__ srcp, const int* __restrict__ dstp,
                           const unsigned short* __restrict__ se01b, int layer_off,
                           const float* __restrict__ si, const float* __restrict__ sj,
                           float4* __restrict__ attp) {
    int i = blockIdx.x * blockDim.x + threadIdx.x;
    if (i >= N_EDGES) return;
    int s = srcp[i], u = dstp[i];
    float4 siv = ((const float4*)si)[s];
    float4 sjv = ((const float4*)sj)[u];
    u16x8 seb = *(const u16x8*)(se01b + (size_t)i * 8);
    float t0 = siv.x + sjv.x + bf2f(seb[layer_off + 0]);
    float t1 = siv.y + sjv.y + bf2f(seb[layer_off + 1]);
    float t2 = siv.z + sjv.z + bf2f(seb[layer_off + 2]);
    float t3 = siv.w + sjv.w + bf2f(seb[layer_off + 3]);
    t0 = t0 > 0.f ? t0 : LRELU_ALPHA * t0;
    t1 = t1 > 0.f ? t1 : LRELU_ALPHA * t1;
    t2 = t2 > 0.f ? t2 : LRELU_ALPHA * t2;
    t3 = t3 > 0.f ? t3 : LRELU_ALPHA * t3;
    float m = fmaxf(fmaxf(t0, t1), fmaxf(t2, t3));
    float p0 = __expf(t0 - m), p1 = __expf(t1 - m), p2 = __expf(t2 - m), p3 = __expf(t3 - m);
    float inv = 1.0f / (p0 + p1 + p2 + p3);
    attp[i] = make_float4(p0 * inv, p1 * inv, p2 * inv, p3 * inv);
}

// ---------------- edge aggregation, 4 heads, concat + ELU ----------------
// one wave per node, 4 edge-slots x 16 lanes; att precomputed (one broadcast float4/edge)
__global__ __launch_bounds__(256) void edge_agg_concat(
    const unsigned short* __restrict__ Whb, const float4* __restrict__ attp,
    const int* __restrict__ row_ptr, const int* __restrict__ dstp,
    unsigned short* __restrict__ out) {
    int v = blockIdx.x * 4 + (threadIdx.x >> 6);
    if (v >= N_NODES) return;
    int l = threadIdx.x & 63;
    int slot = l >> 4, p = l & 15;
    int beg = row_ptr[v], end = row_ptr[v + 1];
    float acc0[8] = {}, acc1[8] = {};
    int i = beg + slot;
    int u_n = 0;
    float4 at_n = make_float4(0.f, 0.f, 0.f, 0.f);
    if (i < end) { u_n = dstp[i]; at_n = attp[i]; }
    for (; i < end; i += 4) {
        int u = u_n;
        float4 at4 = at_n;
        if (i + 4 < end) { u_n = dstp[i + 4]; at_n = attp[i + 4]; }
        const unsigned short* row = Whb + (size_t)u * 256;
        u16x8 w0 = *(const u16x8*)(row + p * 8);         // heads 0/1
        u16x8 w1 = *(const u16x8*)(row + 128 + p * 8);   // heads 2/3
        float atA = (p & 8) ? at4.y : at4.x;
        float atB = (p & 8) ? at4.w : at4.z;
#pragma unroll
        for (int j = 0; j < 8; ++j) acc0[j] += atA * bf2f(w0[j]);
#pragma unroll
        for (int j = 0; j < 8; ++j) acc1[j] += atB * bf2f(w1[j]);
    }
#pragma unroll
    for (int j = 0; j < 8; ++j) {
        acc0[j] += __shfl_xor(acc0[j], 16, 64);
        acc0[j] += __shfl_xor(acc0[j], 32, 64);
        acc1[j] += __shfl_xor(acc1[j], 16, 64);
        acc1[j] += __shfl_xor(acc1[j], 32, 64);
    }
    if (slot == 0) {
        u16x8 o0, o1;
#pragma unroll
        for (int j = 0; j < 8; ++j) {
            o0[j] = f2bf(eluf(acc0[j]));
            o1[j] = f2bf(eluf(acc1[j]));
        }
        *(u16x8*)(out + (size_t)v * 256 + p * 8) = o0;
        *(u16x8*)(out + (size_t)v * 256 + 128 + p * 8) = o1;
    }
}

// ---------------- edge aggregation, single head: 8 slots x 8 lanes ----------------
__global__ __launch_bounds__(256) void edge_agg_single(
    const unsigned short* __restrict__ Whb, const int* __restrict__ row_ptr,
    const int* __restrict__ dstp, float* __restrict__ out) {
    int v = blockIdx.x * 4 + (threadIdx.x >> 6);
    if (v >= N_NODES) return;
    int l = threadIdx.x & 63;
    int slot = l >> 3, p = l & 7;
    int beg = row_ptr[v], end = row_ptr[v + 1];
    float acc[8] = {};
    int i = beg + slot;
    int u_n = 0;
    if (i < end) u_n = dstp[i];
    for (; i < end; i += 8) {
        int u = u_n;
        if (i + 8 < end) u_n = dstp[i + 8];
        u16x8 w = *(const u16x8*)(Whb + (size_t)u * 64 + p * 8);
#pragma unroll
        for (int j = 0; j < 8; ++j) acc[j] += bf2f(w[j]);
    }
#pragma unroll
    for (int j = 0; j < 8; ++j) {
        acc[j] += __shfl_xor(acc[j], 8, 64);
        acc[j] += __shfl_xor(acc[j], 16, 64);
        acc[j] += __shfl_xor(acc[j], 32, 64);
    }
    if (l < 8) {
        float4 o0 = make_float4(acc[0], acc[1], acc[2], acc[3]);
        float4 o1 = make_float4(acc[4], acc[5], acc[6], acc[7]);
        *(float4*)(out + (size_t)v * 64 + p * 8) = o0;
        *(float4*)(out + (size_t)v * 64 + p * 8 + 4) = o1;
    }
}

// ---------------- mean pool per graph (batch sorted), 16 waves per graph ----------------
__global__ __launch_bounds__(1024) void pool_kernel(const float* __restrict__ h3,
                                                    const int* __restrict__ batch,
                                                    float* __restrict__ pooled) {
    int g = blockIdx.x;
    int lane = threadIdx.x & 63;
    int wave = threadIdx.x >> 6;
    int lo = 0, hi = N_NODES;
    while (lo < hi) { int mid = (lo + hi) >> 1; if (batch[mid] < g) lo = mid + 1; else hi = mid; }
    int start = lo;
    lo = start; hi = N_NODES;
    while (lo < hi) { int mid = (lo + hi) >> 1; if (batch[mid] < g + 1) lo = mid + 1; else hi = mid; }
    int endi = lo;
    float s = 0.f;
    for (int v = start + wave; v < endi; v += 16) s += h3[(size_t)v * 64 + lane];
    __shared__ float red[16][64];
    red[wave][lane] = s;
    __syncthreads();
    if (wave == 0) {
        float t = red[0][lane];
#pragma unroll
        for (int w = 1; w < 16; ++w) t += red[w][lane];
        float c = (float)((endi - start) > 1 ? (endi - start) : 1);
        pooled[g * 64 + lane] = t / c;
    }
}

// ---------------- classifier + log_softmax ----------------
__global__ void classify_kernel(const float* __restrict__ pooled, const float* __restrict__ cw,
                                const float* __restrict__ cb, float* __restrict__ out) {
    int g = threadIdx.x;
    if (g >= NUM_GRAPHS) return;
    float lg[NUM_CLASSES];
#pragma unroll
    for (int c = 0; c < NUM_CLASSES; ++c) lg[c] = cb[c];
    for (int d = 0; d < OUT_F; ++d) {
        float p = pooled[g * 64 + d];
#pragma unroll
        for (int c = 0; c < NUM_CLASSES; ++c) lg[c] += p * cw[d * NUM_CLASSES + c];
    }
    float m = lg[0];
#pragma unroll
    for (int c = 1; c < NUM_CLASSES; ++c) m = fmaxf(m, lg[c]);
    float s = 0.f;
#pragma unroll
    for (int c = 0; c < NUM_CLASSES; ++c) s += expf(lg[c] - m);
    float lse = m + logf(s);
#pragma unroll
    for (int c = 0; c < NUM_CLASSES; ++c) out[g * NUM_CLASSES + c] = lg[c] - lse;
}

extern "C" void kernel_launch(void* const* d_in, const int* in_sizes, int n_in,
                              void* d_out, int out_size, void* d_ws, size_t ws_size,
                              hipStream_t stream) {
    const float* x   = (const float*)d_in[0];
    const int*   ei  = (const int*)d_in[1];
    const float* ea  = (const float*)d_in[2];
    const int* batch = (const int*)d_in[3];
    const float* W0  = (const float*)d_in[4];
    const float* a0  = (const float*)d_in[5];
    const float* W1  = (const float*)d_in[6];
    const float* a1  = (const float*)d_in[7];
    const float* W2  = (const float*)d_in[8];
    const float* cw  = (const float*)d_in[10];
    const float* cb  = (const float*)d_in[11];
    float* out = (float*)d_out;

    const int* srcg = ei;
    const int* dstg = ei + N_EDGES;

    char* ws = (char*)d_ws;
    size_t off = 0;
    auto alloc = [&](size_t bytes) -> char* {
        char* p = ws + off;
        off += (bytes + 255) & ~(size_t)255;
        return p;
    };
    unsigned short* W0b  = (unsigned short*)alloc(256 * 256 * 2);
    unsigned short* W1b  = (unsigned short*)alloc(256 * 256 * 2);
    unsigned short* W2b  = (unsigned short*)alloc(256 * 64 * 2);
    unsigned short* Whb  = (unsigned short*)alloc((size_t)N_NODES * 256 * 2);
    unsigned short* hAb  = (unsigned short*)alloc((size_t)N_NODES * 256 * 2);
    unsigned short* hBb  = (unsigned short*)alloc((size_t)N_NODES * 256 * 2);
    unsigned short* Wh2b = (unsigned short*)alloc((size_t)N_NODES * 64 * 2);
    float* si   = (float*)alloc((size_t)N_NODES * HEADS * 4);
    float* sj   = (float*)alloc((size_t)N_NODES * HEADS * 4);
    unsigned short* se01b = (unsigned short*)alloc((size_t)N_EDGES * 8 * 2);
    float* attp = (float*)alloc((size_t)N_EDGES * HEADS * 4);
    int* row_ptr = (int*)alloc((N_NODES + 1) * 4);
    int* cursor  = (int*)alloc(N_NODES * 4);
    int* cnt  = (int*)alloc(N_NODES * 4);
    int* srcp = (int*)alloc(N_EDGES * 4);
    int* dstp = (int*)alloc(N_EDGES * 4);
    float* h3 = (float*)alloc((size_t)N_NODES * 64 * 4);
    float* pooled = (float*)alloc(NUM_GRAPHS * 64 * 4);

    // prep: weight converts + zero cnt (one dispatch)
    prep_kernel<<<144 + (N_NODES / 4 + 255) / 256, 256, 0, stream>>>(W0, W1, W2, W0b, W1b, W2b, cnt);

    // CSR build; scatter also precomputes both layers' edge-feature scores (bf16, 16B store)
    count_kernel<<<(N_EDGES / 4 + 255) / 256, 256, 0, stream>>>((const int4*)srcg, cnt);
    scan_kernel<<<1, 1024, 0, stream>>>(cnt, row_ptr, cursor);
    scatter_kernel<<<(N_EDGES + 255) / 256, 256, 0, stream>>>(srcg, dstg, ea, a0, a1, cursor,
                                                              srcp, dstp, se01b);

    dim3 ggrid((N_NODES + 127) / 128, 4);
    dim3 ggrid2((N_NODES + 127) / 128, 1);
    int atb = (N_EDGES + 255) / 256;
    int agb = (N_NODES + 3) / 4;

    // layer 0 (A = x fp32, scores fused)
    gemm_bf16<true, true><<<ggrid, 256, 0, stream>>>(x, W0b, Whb, a0, si, sj, N_NODES, 256, 256);
    att_kernel<<<atb, 256, 0, stream>>>(srcp, dstp, se01b, 0, si, sj, (float4*)attp);
    edge_agg_concat<<<agb, 256, 0, stream>>>(Whb, (const float4*)attp, row_ptr, dstp, hAb);

    // layer 1
    gemm_bf16<false, true><<<ggrid, 256, 0, stream>>>(hAb, W1b, Whb, a1, si, sj, N_NODES, 256, 256);
    att_kernel<<<atb, 256, 0, stream>>>(srcp, dstp, se01b, 4, si, sj, (float4*)attp);
    edge_agg_concat<<<agb, 256, 0, stream>>>(Whb, (const float4*)attp, row_ptr, dstp, hBb);

    // layer 2 (single head, att == 1, mean over 1 head = identity)
    gemm_bf16<false, false><<<ggrid2, 256, 0, stream>>>(hBb, W2b, Wh2b, nullptr, nullptr, nullptr,
                                                        N_NODES, 64, 256);
    edge_agg_single<<<agb, 256, 0, stream>>>(Wh2b, row_ptr, dstp, h3);

    // pooling + classifier
    pool_kernel<<<NUM_GRAPHS, 1024, 0, stream>>>(h3, batch, pooled);
    classify_kernel<<<1, 64, 0, stream>>>(pooled, cw, cb, out);
}

// Round 13
// 199.920 us; speedup vs baseline: 1.0895x; 1.0553x over previous
//
#include <hip/hip_runtime.h>
#include <hip/hip_bf16.h>
#include <math.h>

#define N_NODES 20000
#define N_EDGES 320000
#define IN_F 256
#define HID 64
#define HEADS 4
#define OUT_F 64
#define EDGE_F 16
#define NUM_CLASSES 10
#define NUM_GRAPHS 40
#define LRELU_ALPHA 0.2f

typedef short bf16x8 __attribute__((ext_vector_type(8)));
typedef unsigned short u16x8 __attribute__((ext_vector_type(8)));
typedef float f32x4 __attribute__((ext_vector_type(4)));

static __device__ __forceinline__ float bf2f(unsigned short u) {
    union { unsigned int i; float f; } v; v.i = ((unsigned int)u) << 16; return v.f;
}
static __device__ __forceinline__ unsigned short f2bf(float f) {
    union { float f; unsigned int i; } v; v.f = f;
    unsigned int r = v.i + 0x7FFF + ((v.i >> 16) & 1);
    return (unsigned short)(r >> 16);
}
static __device__ __forceinline__ float eluf(float a) {
    return a > 0.f ? a : __expf(a) - 1.0f;
}

// ---------------- prep: weight converts (bf16) + zero cnt, one dispatch ----------------
__global__ void prep_kernel(const float* __restrict__ W0, const float* __restrict__ W1,
                            const float* __restrict__ W2, unsigned short* __restrict__ W0b,
                            unsigned short* __restrict__ W1b, unsigned short* __restrict__ W2b,
                            int* __restrict__ cnt) {
    int b = blockIdx.x;
    if (b < 144) {
        int i = b * 256 + threadIdx.x;  // float4 units
        const float* src; unsigned short* dst; int off;
        if (i < 16384)      { src = W0; dst = W0b; off = i; }
        else if (i < 32768) { src = W1; dst = W1b; off = i - 16384; }
        else                { src = W2; dst = W2b; off = i - 32768; }
        float4 v = ((const float4*)src)[off];
        ushort4 o;
        o.x = f2bf(v.x); o.y = f2bf(v.y); o.z = f2bf(v.z); o.w = f2bf(v.w);
        ((ushort4*)dst)[off] = o;
    } else {
        int j = (b - 144) * 256 + threadIdx.x;  // int4 units
        if (j < N_NODES / 4) ((int4*)cnt)[j] = make_int4(0, 0, 0, 0);
    }
}

// ---------------- CSR build, pass 1: count + per-edge rank (atomic return value) ----------------
__global__ void count_rank_kernel(const int4* __restrict__ src4, int* __restrict__ cnt,
                                  int4* __restrict__ rank4) {
    int i = blockIdx.x * blockDim.x + threadIdx.x;
    if (i < N_EDGES / 4) {
        int4 s = src4[i];
        int4 r;
        r.x = atomicAdd(&cnt[s.x], 1);
        r.y = atomicAdd(&cnt[s.y], 1);
        r.z = atomicAdd(&cnt[s.z], 1);
        r.w = atomicAdd(&cnt[s.w], 1);
        rank4[i] = r;
    }
}

// scan: row_ptr (inclusive shifted) + cursor = exclusive prefix (row start offsets)
__global__ __launch_bounds__(1024) void scan_kernel(const int* __restrict__ cnt,
                                                    int* __restrict__ row_ptr,
                                                    int* __restrict__ cursor) {
    __shared__ int wsum[16];
    __shared__ int carry_s;
    int t = threadIdx.x;
    int lane = t & 63, wave = t >> 6;
    if (t == 0) { carry_s = 0; row_ptr[0] = 0; }
    __syncthreads();
    for (int base = 0; base < N_NODES; base += 1024) {
        int idx = base + t;
        int x0 = (idx < N_NODES) ? cnt[idx] : 0;
        int x = x0;
#pragma unroll
        for (int off = 1; off < 64; off <<= 1) {
            int y = __shfl_up(x, off, 64);
            if (lane >= off) x += y;
        }
        if (lane == 63) wsum[wave] = x;
        __syncthreads();
        if (wave == 0 && lane < 16) {
            int s = wsum[lane];
#pragma unroll
            for (int off = 1; off < 16; off <<= 1) {
                int y = __shfl_up(s, off, 64);
                if (lane >= off) s += y;
            }
            wsum[lane] = s;
        }
        __syncthreads();
        int waveoff = (wave > 0) ? wsum[wave - 1] : 0;
        int carry = carry_s;
        if (idx < N_NODES) {
            int incl = x + waveoff + carry;
            row_ptr[idx + 1] = incl;
            cursor[idx] = incl - x0;   // row start
        }
        __syncthreads();
        if (t == 0) carry_s = carry + wsum[15];
        __syncthreads();
    }
}

// ---------------- CSR build, pass 2: payload scatter, NO atomic ----------------
// pos = cursor[src[e]] + rank[e]; all reads coalesced (cursor gather is 80KB, L2-hit);
// 3 independent scattered stores with full memory-level parallelism
__global__ void scatter_payload(const int* __restrict__ src, const int* __restrict__ dst,
                                const int* __restrict__ rank, const float* __restrict__ ea,
                                const float* __restrict__ a0, const float* __restrict__ a1,
                                const int* __restrict__ cursor, int* __restrict__ srcp,
                                int* __restrict__ dstp, unsigned short* __restrict__ se01b) {
    __shared__ float ae[2][4][16];
    int tid = threadIdx.x;
    if (tid < 64) ae[0][tid >> 4][tid & 15] = a0[(tid >> 4) * 144 + 128 + (tid & 15)];
    else if (tid < 128) { int t = tid - 64; ae[1][t >> 4][t & 15] = a1[(t >> 4) * 144 + 128 + (t & 15)]; }
    __syncthreads();
    int e = blockIdx.x * blockDim.x + tid;
    if (e >= N_EDGES) return;
    int s = src[e];
    int pos = cursor[s] + rank[e];
    srcp[pos] = s;
    dstp[pos] = dst[e];
    float x[16];
#pragma unroll
    for (int k = 0; k < 16; k += 4) {
        float4 v = *(const float4*)(ea + (size_t)e * 16 + k);
        x[k] = v.x; x[k + 1] = v.y; x[k + 2] = v.z; x[k + 3] = v.w;
    }
    float o[8] = {};
#pragma unroll
    for (int k = 0; k < 16; ++k) {
        o[0] += x[k] * ae[0][0][k]; o[1] += x[k] * ae[0][1][k];
        o[2] += x[k] * ae[0][2][k]; o[3] += x[k] * ae[0][3][k];
        o[4] += x[k] * ae[1][0][k]; o[5] += x[k] * ae[1][1][k];
        o[6] += x[k] * ae[1][2][k]; o[7] += x[k] * ae[1][3][k];
    }
    u16x8 ob;
#pragma unroll
    for (int q = 0; q < 8; ++q) ob[q] = f2bf(o[q]);
    *(u16x8*)(se01b + (size_t)pos * 8) = ob;
}

// ---------------- bf16 MFMA GEMM (BM=128,BN=64,BK=32) + fused attention scores ----------------
template <bool AF32, bool SCORES>
__global__ __launch_bounds__(256) void gemm_bf16(const void* __restrict__ Aptr,
                                                 const unsigned short* __restrict__ B,
                                                 unsigned short* __restrict__ C,
                                                 const float* __restrict__ avec,
                                                 float* __restrict__ si, float* __restrict__ sj,
                                                 int M, int N, int K) {
    __shared__ unsigned short As[128][40];
    __shared__ unsigned short Bs[64][40];   // [n][k] (transposed)
    __shared__ unsigned short Cs[128][72];
    __shared__ float sa[128];
    int tid = threadIdx.x;
    if (SCORES && tid < 128) sa[tid] = avec[blockIdx.y * 144 + tid];
    int bm = blockIdx.x * 128, bn = blockIdx.y * 64;
    int w = tid >> 6, l = tid & 63;
    int wr = w * 32;
    int lr = l & 15, lk = (l >> 4) * 8;
    f32x4 acc[2][4] = {};
    int ar = tid >> 1, akc = (tid & 1) * 16;
    int bk = tid >> 3, bn8 = tid & 7, bnc = bn8 * 8;

    for (int k0 = 0; k0 < K; k0 += 32) {
        bf16x8 av0 = {}, av1 = {};
        if (bm + ar < M) {
            if constexpr (AF32) {
                const float* Af = (const float*)Aptr + (size_t)(bm + ar) * K + k0 + akc;
                float4 f0 = ((const float4*)Af)[0];
                float4 f1 = ((const float4*)Af)[1];
                float4 f2 = ((const float4*)Af)[2];
                float4 f3 = ((const float4*)Af)[3];
                av0[0] = (short)f2bf(f0.x); av0[1] = (short)f2bf(f0.y);
                av0[2] = (short)f2bf(f0.z); av0[3] = (short)f2bf(f0.w);
                av0[4] = (short)f2bf(f1.x); av0[5] = (short)f2bf(f1.y);
                av0[6] = (short)f2bf(f1.z); av0[7] = (short)f2bf(f1.w);
                av1[0] = (short)f2bf(f2.x); av1[1] = (short)f2bf(f2.y);
                av1[2] = (short)f2bf(f2.z); av1[3] = (short)f2bf(f2.w);
                av1[4] = (short)f2bf(f3.x); av1[5] = (short)f2bf(f3.y);
                av1[6] = (short)f2bf(f3.z); av1[7] = (short)f2bf(f3.w);
            } else {
                const unsigned short* Ab = (const unsigned short*)Aptr + (size_t)(bm + ar) * K + k0 + akc;
                av0 = *(const bf16x8*)Ab;
                av1 = *(const bf16x8*)(Ab + 8);
            }
        }
        *(bf16x8*)&As[ar][akc] = av0;
        *(bf16x8*)&As[ar][akc + 8] = av1;
        bf16x8 bv = *(const bf16x8*)(B + (size_t)(k0 + bk) * N + bn + bnc);
#pragma unroll
        for (int j = 0; j < 8; ++j) {
            int jj = (j + bn8) & 7;  // rotate write order to spread banks
            Bs[bnc + jj][bk] = (unsigned short)bv[jj];
        }
        __syncthreads();
        bf16x8 a0 = *(const bf16x8*)&As[wr + lr][lk];
        bf16x8 a1 = *(const bf16x8*)&As[wr + 16 + lr][lk];
        bf16x8 b0 = *(const bf16x8*)&Bs[lr][lk];
        bf16x8 b1 = *(const bf16x8*)&Bs[16 + lr][lk];
        bf16x8 b2 = *(const bf16x8*)&Bs[32 + lr][lk];
        bf16x8 b3 = *(const bf16x8*)&Bs[48 + lr][lk];
        acc[0][0] = __builtin_amdgcn_mfma_f32_16x16x32_bf16(a0, b0, acc[0][0], 0, 0, 0);
        acc[0][1] = __builtin_amdgcn_mfma_f32_16x16x32_bf16(a0, b1, acc[0][1], 0, 0, 0);
        acc[0][2] = __builtin_amdgcn_mfma_f32_16x16x32_bf16(a0, b2, acc[0][2], 0, 0, 0);
        acc[0][3] = __builtin_amdgcn_mfma_f32_16x16x32_bf16(a0, b3, acc[0][3], 0, 0, 0);
        acc[1][0] = __builtin_amdgcn_mfma_f32_16x16x32_bf16(a1, b0, acc[1][0], 0, 0, 0);
        acc[1][1] = __builtin_amdgcn_mfma_f32_16x16x32_bf16(a1, b1, acc[1][1], 0, 0, 0);
        acc[1][2] = __builtin_amdgcn_mfma_f32_16x16x32_bf16(a1, b2, acc[1][2], 0, 0, 0);
        acc[1][3] = __builtin_amdgcn_mfma_f32_16x16x32_bf16(a1, b3, acc[1][3], 0, 0, 0);
        __syncthreads();
    }
    // D layout: col = lane&15, row = (lane>>4)*4 + reg
#pragma unroll
    for (int i = 0; i < 2; ++i)
#pragma unroll
        for (int j = 0; j < 4; ++j)
#pragma unroll
            for (int r = 0; r < 4; ++r)
                Cs[wr + i * 16 + (l >> 4) * 4 + r][j * 16 + (l & 15)] = f2bf(acc[i][j][r]);
    __syncthreads();
    {
        int row = tid >> 3, cc = (tid & 7) * 8;
#pragma unroll
        for (int p = 0; p < 4; ++p, row += 32) {
            if (bm + row < M) {
                bf16x8 o = *(const bf16x8*)&Cs[row][cc];
                *(bf16x8*)(C + (size_t)(bm + row) * N + bn + cc) = o;
            }
        }
    }
    if (SCORES) {
        int r = tid >> 1, half = tid & 1;
        float s0 = 0.f, s1 = 0.f;
#pragma unroll
        for (int k = 0; k < 32; ++k) {
            float f = bf2f(Cs[r][half * 32 + k]);
            s0 += f * sa[half * 32 + k];
            s1 += f * sa[64 + half * 32 + k];
        }
        s0 += __shfl_xor(s0, 1, 64);
        s1 += __shfl_xor(s1, 1, 64);
        if (half == 0 && bm + r < M) {
            si[(size_t)(bm + r) * 4 + blockIdx.y] = s0;
            sj[(size_t)(bm + r) * 4 + blockIdx.y] = s1;
        }
    }
}

// ---------------- per-edge attention (CSR order, coalesced; bf16 se01) ----------------
__global__ void att_kernel(const int* __restrict__ srcp, const int* __restrict__ dstp,
                           const unsigned short* __restrict__ se01b, int layer_off,
                           const float* __restrict__ si, const float* __restrict__ sj,
                           float4* __restrict__ attp) {
    int i = blockIdx.x * blockDim.x + threadIdx.x;
    if (i >= N_EDGES) return;
    int s = srcp[i], u = dstp[i];
    float4 siv = ((const float4*)si)[s];
    float4 sjv = ((const float4*)sj)[u];
    u16x8 seb = *(const u16x8*)(se01b + (size_t)i * 8);
    float t0 = siv.x + sjv.x + bf2f(seb[layer_off + 0]);
    float t1 = siv.y + sjv.y + bf2f(seb[layer_off + 1]);
    float t2 = siv.z + sjv.z + bf2f(seb[layer_off + 2]);
    float t3 = siv.w + sjv.w + bf2f(seb[layer_off + 3]);
    t0 = t0 > 0.f ? t0 : LRELU_ALPHA * t0;
    t1 = t1 > 0.f ? t1 : LRELU_ALPHA * t1;
    t2 = t2 > 0.f ? t2 : LRELU_ALPHA * t2;
    t3 = t3 > 0.f ? t3 : LRELU_ALPHA * t3;
    float m = fmaxf(fmaxf(t0, t1), fmaxf(t2, t3));
    float p0 = __expf(t0 - m), p1 = __expf(t1 - m), p2 = __expf(t2 - m), p3 = __expf(t3 - m);
    float inv = 1.0f / (p0 + p1 + p2 + p3);
    attp[i] = make_float4(p0 * inv, p1 * inv, p2 * inv, p3 * inv);
}

// ---------------- edge aggregation, 4 heads, concat + ELU ----------------
// one wave per node, 4 edge-slots x 16 lanes; att precomputed (one broadcast float4/edge)
__global__ __launch_bounds__(256) void edge_agg_concat(
    const unsigned short* __restrict__ Whb, const float4* __restrict__ attp,
    const int* __restrict__ row_ptr, const int* __restrict__ dstp,
    unsigned short* __restrict__ out) {
    int v = blockIdx.x * 4 + (threadIdx.x >> 6);
    if (v >= N_NODES) return;
    int l = threadIdx.x & 63;
    int slot = l >> 4, p = l & 15;
    int beg = row_ptr[v], end = row_ptr[v + 1];
    float acc0[8] = {}, acc1[8] = {};
    int i = beg + slot;
    int u_n = 0;
    float4 at_n = make_float4(0.f, 0.f, 0.f, 0.f);
    if (i < end) { u_n = dstp[i]; at_n = attp[i]; }
    for (; i < end; i += 4) {
        int u = u_n;
        float4 at4 = at_n;
        if (i + 4 < end) { u_n = dstp[i + 4]; at_n = attp[i + 4]; }
        const unsigned short* row = Whb + (size_t)u * 256;
        u16x8 w0 = *(const u16x8*)(row + p * 8);         // heads 0/1
        u16x8 w1 = *(const u16x8*)(row + 128 + p * 8);   // heads 2/3
        float atA = (p & 8) ? at4.y : at4.x;
        float atB = (p & 8) ? at4.w : at4.z;
#pragma unroll
        for (int j = 0; j < 8; ++j) acc0[j] += atA * bf2f(w0[j]);
#pragma unroll
        for (int j = 0; j < 8; ++j) acc1[j] += atB * bf2f(w1[j]);
    }
#pragma unroll
    for (int j = 0; j < 8; ++j) {
        acc0[j] += __shfl_xor(acc0[j], 16, 64);
        acc0[j] += __shfl_xor(acc0[j], 32, 64);
        acc1[j] += __shfl_xor(acc1[j], 16, 64);
        acc1[j] += __shfl_xor(acc1[j], 32, 64);
    }
    if (slot == 0) {
        u16x8 o0, o1;
#pragma unroll
        for (int j = 0; j < 8; ++j) {
            o0[j] = f2bf(eluf(acc0[j]));
            o1[j] = f2bf(eluf(acc1[j]));
        }
        *(u16x8*)(out + (size_t)v * 256 + p * 8) = o0;
        *(u16x8*)(out + (size_t)v * 256 + 128 + p * 8) = o1;
    }
}

// ---------------- edge aggregation, single head: 8 slots x 8 lanes ----------------
__global__ __launch_bounds__(256) void edge_agg_single(
    const unsigned short* __restrict__ Whb, const int* __restrict__ row_ptr,
    const int* __restrict__ dstp, float* __restrict__ out) {
    int v = blockIdx.x * 4 + (threadIdx.x >> 6);
    if (v >= N_NODES) return;
    int l = threadIdx.x & 63;
    int slot = l >> 3, p = l & 7;
    int beg = row_ptr[v], end = row_ptr[v + 1];
    float acc[8] = {};
    int i = beg + slot;
    int u_n = 0;
    if (i < end) u_n = dstp[i];
    for (; i < end; i += 8) {
        int u = u_n;
        if (i + 8 < end) u_n = dstp[i + 8];
        u16x8 w = *(const u16x8*)(Whb + (size_t)u * 64 + p * 8);
#pragma unroll
        for (int j = 0; j < 8; ++j) acc[j] += bf2f(w[j]);
    }
#pragma unroll
    for (int j = 0; j < 8; ++j) {
        acc[j] += __shfl_xor(acc[j], 8, 64);
        acc[j] += __shfl_xor(acc[j], 16, 64);
        acc[j] += __shfl_xor(acc[j], 32, 64);
    }
    if (l < 8) {
        float4 o0 = make_float4(acc[0], acc[1], acc[2], acc[3]);
        float4 o1 = make_float4(acc[4], acc[5], acc[6], acc[7]);
        *(float4*)(out + (size_t)v * 64 + p * 8) = o0;
        *(float4*)(out + (size_t)v * 64 + p * 8 + 4) = o1;
    }
}

// ---------------- mean pool per graph (batch sorted), 16 waves per graph ----------------
__global__ __launch_bounds__(1024) void pool_kernel(const float* __restrict__ h3,
                                                    const int* __restrict__ batch,
                                                    float* __restrict__ pooled) {
    int g = blockIdx.x;
    int lane = threadIdx.x & 63;
    int wave = threadIdx.x >> 6;
    int lo = 0, hi = N_NODES;
    while (lo < hi) { int mid = (lo + hi) >> 1; if (batch[mid] < g) lo = mid + 1; else hi = mid; }
    int start = lo;
    lo = start; hi = N_NODES;
    while (lo < hi) { int mid = (lo + hi) >> 1; if (batch[mid] < g + 1) lo = mid + 1; else hi = mid; }
    int endi = lo;
    float s = 0.f;
    for (int v = start + wave; v < endi; v += 16) s += h3[(size_t)v * 64 + lane];
    __shared__ float red[16][64];
    red[wave][lane] = s;
    __syncthreads();
    if (wave == 0) {
        float t = red[0][lane];
#pragma unroll
        for (int w = 1; w < 16; ++w) t += red[w][lane];
        float c = (float)((endi - start) > 1 ? (endi - start) : 1);
        pooled[g * 64 + lane] = t / c;
    }
}

// ---------------- classifier + log_softmax ----------------
__global__ void classify_kernel(const float* __restrict__ pooled, const float* __restrict__ cw,
                                const float* __restrict__ cb, float* __restrict__ out) {
    int g = threadIdx.x;
    if (g >= NUM_GRAPHS) return;
    float lg[NUM_CLASSES];
#pragma unroll
    for (int c = 0; c < NUM_CLASSES; ++c) lg[c] = cb[c];
    for (int d = 0; d < OUT_F; ++d) {
        float p = pooled[g * 64 + d];
#pragma unroll
        for (int c = 0; c < NUM_CLASSES; ++c) lg[c] += p * cw[d * NUM_CLASSES + c];
    }
    float m = lg[0];
#pragma unroll
    for (int c = 1; c < NUM_CLASSES; ++c) m = fmaxf(m, lg[c]);
    float s = 0.f;
#pragma unroll
    for (int c = 0; c < NUM_CLASSES; ++c) s += expf(lg[c] - m);
    float lse = m + logf(s);
#pragma unroll
    for (int c = 0; c < NUM_CLASSES; ++c) out[g * NUM_CLASSES + c] = lg[c] - lse;
}

extern "C" void kernel_launch(void* const* d_in, const int* in_sizes, int n_in,
                              void* d_out, int out_size, void* d_ws, size_t ws_size,
                              hipStream_t stream) {
    const float* x   = (const float*)d_in[0];
    const int*   ei  = (const int*)d_in[1];
    const float* ea  = (const float*)d_in[2];
    const int* batch = (const int*)d_in[3];
    const float* W0  = (const float*)d_in[4];
    const float* a0  = (const float*)d_in[5];
    const float* W1  = (const float*)d_in[6];
    const float* a1  = (const float*)d_in[7];
    const float* W2  = (const float*)d_in[8];
    const float* cw  = (const float*)d_in[10];
    const float* cb  = (const float*)d_in[11];
    float* out = (float*)d_out;

    const int* srcg = ei;
    const int* dstg = ei + N_EDGES;

    char* ws = (char*)d_ws;
    size_t off = 0;
    auto alloc = [&](size_t bytes) -> char* {
        char* p = ws + off;
        off += (bytes + 255) & ~(size_t)255;
        return p;
    };
    unsigned short* W0b  = (unsigned short*)alloc(256 * 256 * 2);
    unsigned short* W1b  = (unsigned short*)alloc(256 * 256 * 2);
    unsigned short* W2b  = (unsigned short*)alloc(256 * 64 * 2);
    unsigned short* Whb  = (unsigned short*)alloc((size_t)N_NODES * 256 * 2);
    unsigned short* hAb  = (unsigned short*)alloc((size_t)N_NODES * 256 * 2);
    unsigned short* hBb  = (unsigned short*)alloc((size_t)N_NODES * 256 * 2);
    unsigned short* Wh2b = (unsigned short*)alloc((size_t)N_NODES * 64 * 2);
    float* si   = (float*)alloc((size_t)N_NODES * HEADS * 4);
    float* sj   = (float*)alloc((size_t)N_NODES * HEADS * 4);
    unsigned short* se01b = (unsigned short*)alloc((size_t)N_EDGES * 8 * 2);
    float* attp = (float*)alloc((size_t)N_EDGES * HEADS * 4);
    int* row_ptr = (int*)alloc((N_NODES + 1) * 4);
    int* cursor  = (int*)alloc(N_NODES * 4);
    int* cnt  = (int*)alloc(N_NODES * 4);
    int* rank = (int*)alloc(N_EDGES * 4);
    int* srcp = (int*)alloc(N_EDGES * 4);
    int* dstp = (int*)alloc(N_EDGES * 4);
    float* h3 = (float*)alloc((size_t)N_NODES * 64 * 4);
    float* pooled = (float*)alloc(NUM_GRAPHS * 64 * 4);

    // prep: weight converts + zero cnt (one dispatch)
    prep_kernel<<<144 + (N_NODES / 4 + 255) / 256, 256, 0, stream>>>(W0, W1, W2, W0b, W1b, W2b, cnt);

    // CSR build: single atomic pass (count+rank), scan, then atomic-free payload scatter
    count_rank_kernel<<<(N_EDGES / 4 + 255) / 256, 256, 0, stream>>>((const int4*)srcg, cnt,
                                                                     (int4*)rank);
    scan_kernel<<<1, 1024, 0, stream>>>(cnt, row_ptr, cursor);
    scatter_payload<<<(N_EDGES + 255) / 256, 256, 0, stream>>>(srcg, dstg, rank, ea, a0, a1,
                                                               cursor, srcp, dstp, se01b);

    dim3 ggrid((N_NODES + 127) / 128, 4);
    dim3 ggrid2((N_NODES + 127) / 128, 1);
    int atb = (N_EDGES + 255) / 256;
    int agb = (N_NODES + 3) / 4;

    // layer 0 (A = x fp32, scores fused)
    gemm_bf16<true, true><<<ggrid, 256, 0, stream>>>(x, W0b, Whb, a0, si, sj, N_NODES, 256, 256);
    att_kernel<<<atb, 256, 0, stream>>>(srcp, dstp, se01b, 0, si, sj, (float4*)attp);
    edge_agg_concat<<<agb, 256, 0, stream>>>(Whb, (const float4*)attp, row_ptr, dstp, hAb);

    // layer 1
    gemm_bf16<false, true><<<ggrid, 256, 0, stream>>>(hAb, W1b, Whb, a1, si, sj, N_NODES, 256, 256);
    att_kernel<<<atb, 256, 0, stream>>>(srcp, dstp, se01b, 4, si, sj, (float4*)attp);
    edge_agg_concat<<<agb, 256, 0, stream>>>(Whb, (const float4*)attp, row_ptr, dstp, hBb);

    // layer 2 (single head, att == 1, mean over 1 head = identity)
    gemm_bf16<false, false><<<ggrid2, 256, 0, stream>>>(hBb, W2b, Wh2b, nullptr, nullptr, nullptr,
                                                        N_NODES, 64, 256);
    edge_agg_single<<<agb, 256, 0, stream>>>(Wh2b, row_ptr, dstp, h3);

    // pooling + classifier
    pool_kernel<<<NUM_GRAPHS, 1024, 0, stream>>>(h3, batch, pooled);
    classify_kernel<<<1, 64, 0, stream>>>(pooled, cw, cb, out);
}